// Round 24
// baseline (191.969 us; speedup 1.0000x reference)
//
#include <hip/hip_runtime.h>
#include <string.h>

typedef __attribute__((ext_vector_type(4))) float f32x4;
typedef __attribute__((ext_vector_type(8))) _Float16 f16x8;
typedef unsigned short u16;
typedef unsigned int   u32;

#define NBATCH 8
#define ICN 256
#define OCN 128
#define VOLP 36432     // padded per-(n,oc) y volume (elements)
#define WRE 884736     // 27*8*8*512 = 27*256*128
#define XTE 8388608    // 8*256*4096
#define ZBF 4096       // zero-buffer floats (16 KB)
// pool: 4 waves x 2 bufs x (102 pos x 32 ic x 2B = 6528 B) = 52224
#define S1POOL 52224

__host__ __device__ constexpr int cls_yoff2(int c){
  return (c==0)?0:(c==1)?5168:(c==2)?9792:(c==3)?14416:
         (c==4)?18768:(c==5)?23632:(c==6)?27984:32336;
}
__host__ __device__ constexpr int cls_nxyp(int c){
  return ((c&3)==0)?304:((c&3)==3)?256:272;
}

__device__ __forceinline__ u16 f2h(float v){
  _Float16 h = (_Float16)v;
  u16 u; memcpy(&u, &h, 2);
  return u;
}
__device__ __forceinline__ float h2f(u16 u){
  _Float16 h; memcpy(&h, &u, 2);
  return (float)h;
}

#define GLOAD16(gp, lp)                                                        \
  __builtin_amdgcn_global_load_lds(                                            \
      (const __attribute__((address_space(1))) void*)(gp),                     \
      (__attribute__((address_space(3))) void*)(lp), 16, 0, 0)

// ---- merged prep: blocks [0,1024) = prep_x ; [1024,4480) = prep_w ----
__global__ __launch_bounds__(256) void prep_all(const float* __restrict__ x,
                                                const float* __restrict__ w,
                                                u16* __restrict__ xh,
                                                u16* __restrict__ wh,
                                                float* __restrict__ zb){
  __shared__ u16 tile[256*33];
  const int tid = threadIdx.x;
  const int b = blockIdx.x;
  if (b < 1024){
    // prep_x: x[n][ic][4096] fp32 -> xh[n][icc8][4096 p][32 ic] f16 (coalesced)
    const int n = b >> 7, icc = (b >> 4) & 7, pc = b & 15;
    const float* xb = x + ((size_t)(n*256 + icc*32))*4096 + pc*256;
    #pragma unroll 4
    for (int r = 0; r < 32; ++r)
      tile[tid*33 + r] = f2h(xb[(size_t)r*4096 + tid]);
    __syncthreads();
    u16* ob = xh + ((size_t)(n*8 + icc))*131072 + pc*8192;
    #pragma unroll
    for (int j = 0; j < 4; ++j){
      int c = j*256 + tid;
      int p = c >> 2, il8 = (c & 3)*8;
      ushort4 lo, hi;
      lo.x = tile[p*33+il8+0]; lo.y = tile[p*33+il8+1];
      lo.z = tile[p*33+il8+2]; lo.w = tile[p*33+il8+3];
      hi.x = tile[p*33+il8+4]; hi.y = tile[p*33+il8+5];
      hi.z = tile[p*33+il8+6]; hi.w = tile[p*33+il8+7];
      *(ushort4*)&ob[c*8]     = lo;
      *(ushort4*)&ob[c*8 + 4] = hi;
    }
  } else {
    // prep_w: w[oc][ic][27] fp32 -> wh[tap27][icc8][og8][lane64][e8] f16
    const int bb = b - 1024;
    if (bb < 16) zb[bb*256 + tid] = 0.f;
    int idx = bb*256 + tid;   // WRE exactly
    int e = idx&7, ln=(idx>>3)&63, og=(idx>>9)&7, icc=(idx>>12)&7, tt=idx>>15;
    int oc = og*16 + (ln&15);
    int ic = icc*32 + ((ln>>4)&3)*8 + e;
    const int toffs[8] = {0,8,12,16,18,22,24,26};
    const int tcnt[8]  = {8,4,4,2,4,2,2,1};
    int c=0, t=0;
    #pragma unroll
    for (int cc=0; cc<8; ++cc)
      if (tt>=toffs[cc] && tt<toffs[cc]+tcnt[cc]){ c=cc; t=tt-toffs[cc]; }
    int ez=c>>2, ey=(c>>1)&1, ex=c&1;
    int ty=2-ey, tx=2-ex;
    int ax=t%tx, ay=(t/tx)%ty, az=t/(tx*ty);
    int qz = ez?1:(az?2:0), qy = ey?1:(ay?2:0), qx = ex?1:(ax?2:0);
    wh[idx] = f2h(w[((size_t)oc*ICN + ic)*27 + (qz*3+qy)*3+qx]);
  }
}

// ---- per-wave async A staging: 408 chunks of 16 B (6 rows x 17 x 4 icg) ----
// chunk r = pos*4 + icg; LDS byte = wv*13056 + BUFBYTE + r*16 (own buffer)
#define S1_ISSUE(BUFBYTE, ICCV, AZV)                                           \
  {                                                                            \
    _Pragma("unroll")                                                          \
    for (int j_=0; j_<7; ++j_){                                                \
      const int r_ = j_*64 + ln;                                               \
      if (r_ < 408){                                                           \
        const int icg_ = r_&3, pos_ = r_>>2;                                   \
        const int xi_ = pos_%17, yi_ = pos_/17;                                \
        const int zc_ = EZ ? mz : (mz-1+(AZV));                                \
        const int yc_ = my0w + yi_ + (EY-1);                                   \
        const int xc_ = xi_ + (EX-1);                                          \
        const bool inb_ = (u32)zc_<16u && (u32)yc_<16u && (u32)xc_<16u;        \
        const size_t g_ = nbase + (size_t)(ICCV)*131072                        \
                        + (size_t)((zc_*256+yc_*16+xc_)*32 + icg_*8);          \
        const u16* gh_ = inb_ ? (xh+g_) : zb16;                                \
        char* lh_ = pool + wv*13056 + (BUFBYTE) + r_*16;                       \
        GLOAD16(gh_, lh_);                                                     \
      }                                                                        \
    }                                                                          \
  }

// ---- stage 1 body: barrier-free per-wave pipelined conv via f16 MFMA ----
// block 256 (4 independent waves): wave = (mhalf = wv&1)*64m x (ochalf = wv>>1)*64oc
template<int EZ,int EY,int EX>
__device__ __forceinline__ void s1body(char* pool,
                                       const u16* __restrict__ xh,
                                       const u16* __restrict__ wh,
                                       const u16* __restrict__ zb16,
                                       u16* __restrict__ yd, int n0, int mt, int mz, int nl, int tid)
{
  constexpr int TZ=2-EZ, TY=2-EY, TX=2-EX;
  constexpr int DX=17-EX;
  constexpr int DY=17-EY;
  constexpr int NXY=DY*DX;
  constexpr int CLS = EZ*4+EY*2+EX;
  constexpr int YOFF = cls_yoff2(CLS);
  constexpr int NXYP = cls_nxyp(CLS);
  constexpr int W27 = (CLS==0)?0:(CLS==1)?8:(CLS==2)?12:(CLS==3)?16:
                      (CLS==4)?18:(CLS==5)?22:(CLS==6)?24:26;
  constexpr int NST = TZ*8;        // total plane-stages
  u16* AsU = (u16*)pool;           // per wave: 6528 u16 region, 2 bufs x 3264

  const int wv=tid>>6, ln=tid&63;
  const int mhalf = wv&1, ochalf = wv>>1;
  const int mbase = mt*128 + mhalf*64;
  const int my0w = mbase/DX;

  int posA[4];
  #pragma unroll
  for (int fi=0; fi<4; ++fi){
    int m = mbase + fi*16 + (ln&15);
    if (m > NXY-1) m = NXY-1;      // clamp (stores guarded)
    int my=m/DX, mx=m-my*DX;
    posA[fi] = ((my-my0w)*17 + mx)*32 + (ln>>4)*8;   // [pos][icg] in own buffer
  }

  f32x4 acc[4][4];
  #pragma unroll
  for (int i=0;i<4;++i)
    #pragma unroll
    for (int j=0;j<4;++j) acc[i][j]=(f32x4){0.f,0.f,0.f,0.f};

  const size_t nbase = (size_t)(n0+nl)*(ICN*4096);

  S1_ISSUE(0, 0, 0);

  int st = 0;
  #pragma unroll 1
  for (int icc=0; icc<8; ++icc){
    #pragma unroll
    for (int az=0; az<TZ; ++az){
      const int cur = st & 1;
      const bool have_next = (st+1) < NST;
      if (have_next){
        const int nicc = (az+1<TZ)?icc:(icc+1);
        const int naz  = (az+1<TZ)?(az+1):0;
        S1_ISSUE((cur^1)*6528, nicc, naz);
        // per-wave: wait only for THIS wave's previous 7 DMAs; no barrier
        asm volatile("s_waitcnt vmcnt(7)" ::: "memory");
      } else {
        asm volatile("s_waitcnt vmcnt(0)" ::: "memory");
      }
      const int curo = wv*6528 + cur*3264;   // u16 index of own current buffer

      #pragma unroll
      for (int ay=0; ay<TY; ++ay)
      #pragma unroll
      for (int ax=0; ax<TX; ++ax){
        const int t = (az*TY+ay)*TX+ax;
        const int toff = (ay*17+ax)*32;
        f16x8 ah[4];
        #pragma unroll
        for (int fi=0; fi<4; ++fi)
          ah[fi] = *(const f16x8*)&AsU[curo + posA[fi]+toff];
        const u16* bp = wh + (size_t)(((W27+t)*8+icc)*8)*512 + (ochalf*4)*512 + ln*8;
        f16x8 bh[4];
        #pragma unroll
        for (int og=0; og<4; ++og) bh[og] = *(const f16x8*)(bp + og*512);
        #pragma unroll
        for (int fi=0; fi<4; ++fi)
          #pragma unroll
          for (int og=0; og<4; ++og)
            acc[fi][og] = __builtin_amdgcn_mfma_f32_16x16x32_f16(ah[fi], bh[og], acc[fi][og],0,0,0);
      }
      ++st;
    }
  }

  // epilogue: per-wave transpose via own 32x33 buffer (reuses own staging region)
  float* tr = (float*)(pool + wv*13056);
  #pragma unroll
  for (int h=0; h<2; ++h){
    #pragma unroll
    for (int pass=0; pass<2; ++pass){
      #pragma unroll
      for (int fi=0; fi<2; ++fi)
        #pragma unroll
        for (int og2=0; og2<2; ++og2){
          const int og = h*2 + og2;
          #pragma unroll
          for (int j=0; j<4; ++j)
            tr[(og2*16+(ln&15))*33 + fi*16 + (ln>>4)*4 + j] = acc[pass*2+fi][og][j];
        }
      int m = mbase + pass*32 + (ln&31);
      bool valid = m < NXY;
      size_t lbase = (size_t)YOFF + (size_t)mz*NXYP + (valid ? m : 0);
      #pragma unroll 4
      for (int i=0; i<16; ++i){
        int r = 2*i + (ln>>5);          // 0..31
        u16 v = f2h(tr[r*33 + (ln&31)]);
        int oc = ochalf*64 + h*32 + r;
        if (valid)
          __builtin_nontemporal_store(v, yd + (size_t)(nl*128 + oc)*VOLP + lbase);
      }
    }
  }
}

// ---- fused stage 1: class-major intra-XCD ordering (B-sharing L1 locality) ----
__global__ __launch_bounds__(256,3) void stage1f(const u16* __restrict__ xh,
                                                 const u16* __restrict__ wh,
                                                 const u16* __restrict__ zb16,
                                                 u16* __restrict__ yd, int n0){
  __shared__ __align__(16) char pool[S1POOL];
  int bid = blockIdx.x, nl, tid = threadIdx.x;
  if (gridDim.z == 1){ nl = bid & 7; bid >>= 3; }
  else               { nl = blockIdx.z; }
  if      (bid <  51){ int r=bid;     s1body<0,0,0>(pool,xh,wh,zb16,yd,n0,r%3,r/3,nl,tid); }
  else if (bid < 102){ int r=bid-51;  s1body<0,0,1>(pool,xh,wh,zb16,yd,n0,r%3,r/3,nl,tid); }
  else if (bid < 153){ int r=bid-102; s1body<0,1,0>(pool,xh,wh,zb16,yd,n0,r%3,r/3,nl,tid); }
  else if (bid < 187){ int r=bid-153; s1body<0,1,1>(pool,xh,wh,zb16,yd,n0,r%2,r/2,nl,tid); }
  else if (bid < 235){ int r=bid-187; s1body<1,0,0>(pool,xh,wh,zb16,yd,n0,r%3,r/3,nl,tid); }
  else if (bid < 283){ int r=bid-235; s1body<1,0,1>(pool,xh,wh,zb16,yd,n0,r%3,r/3,nl,tid); }
  else if (bid < 331){ int r=bid-283; s1body<1,1,0>(pool,xh,wh,zb16,yd,n0,r%3,r/3,nl,tid); }
  else               { int r=bid-331; s1body<1,1,1>(pool,xh,wh,zb16,yd,n0,r%2,r/2,nl,tid); }
}

// ---- stage 2: vectorized gather + paired separable FIR + bias ----
// grid (4 zg, 128 oc, n): 8 oz per block, 11 uz planes streamed
__global__ __launch_bounds__(256) void stage2d(const u16* __restrict__ yd, const float* __restrict__ bias,
                                               float* __restrict__ out, int n0){
  __shared__ float raw[33][36];
  __shared__ float fx[35][36];
  const int tid=threadIdx.x;
  const int zg=blockIdx.x, oc=blockIdx.y, nl=blockIdx.z;
  const u16* yb = yd + (size_t)(nl*128+oc)*VOLP;
  const float b = bias[oc];
  float* ob = out + (size_t)((n0+nl)*128+oc)*32768;
  for (int t2=tid; t2<1188; t2+=256) raw[t2/36][t2%36] = 0.f;
  for (int t2=tid; t2<1260; t2+=256) fx[t2/36][t2%36] = 0.f;
  __syncthreads();
  float a0[2][2]={{0,0},{0,0}}, a1[2][2]={{0,0},{0,0}}, a2[2][2]={{0,0},{0,0}};

  #pragma unroll 1
  for (int s=0; s<11; ++s){
    int uz = zg*8 - 1 + s;
    if ((u32)uz < 33u){
      const int cz = uz & 1, zi2 = uz >> 1;
      #pragma unroll 1
      for (int ch=tid; ch<273; ch+=256){
        #define GATH(CY,CX,CHL)                                                     \
        {                                                                           \
          constexpr int DXc = 17-(CX);                                              \
          constexpr int NXYc = (17-(CY))*DXc;                                       \
          constexpr int O0 = cls_yoff2((CY)*2+(CX));                                \
          constexpr int O1 = cls_yoff2(4+(CY)*2+(CX));                              \
          constexpr int PS = cls_nxyp((CY)*2+(CX));                                 \
          const int s2 = 4*(CHL);                                                   \
          const int r0 = s2/DXc;                                                    \
          const int c0 = s2 - r0*DXc;                                               \
          const u16* sp = yb + (cz?O1:O0) + zi2*PS + s2;                            \
          ushort4 v = *(const ushort4*)sp;                                          \
          u16 ve[4] = {v.x, v.y, v.z, v.w};                                         \
          _Pragma("unroll")                                                         \
          for (int e=0; e<4; ++e){                                                  \
            int c = c0+e, rr = r0;                                                  \
            if (c >= DXc){ c -= DXc; rr += 1; }                                     \
            if (s2+e < NXYc) raw[2*rr+(CY)][2*c+(CX)+1] = h2f(ve[e]);               \
          }                                                                         \
        }
        if      (ch <  73) GATH(0,0,ch)
        else if (ch < 141) GATH(0,1,ch-73)
        else if (ch < 209) GATH(1,0,ch-141)
        else               GATH(1,1,ch-209)
        #undef GATH
      }
    } else {
      for (int t2=tid; t2<1188; t2+=256) raw[t2/36][t2%36] = 0.f;
    }
    __syncthreads();
    #pragma unroll 1
    for (int t2=tid; t2<528; t2+=256){
      int uy = t2>>4, j = t2&15;
      float2 A = *(const float2*)&raw[uy][2*j];
      float2 B = *(const float2*)&raw[uy][2*j+2];
      float  Cv = raw[uy][2*j+4];
      float f0 = 0.25f*A.x + 0.75f*A.y + 0.75f*B.x + 0.25f*B.y;
      float f1 = 0.25f*A.y + 0.75f*B.x + 0.75f*B.y + 0.25f*Cv;
      *(float2*)&fx[uy+1][2*j] = make_float2(f0, f1);
    }
    __syncthreads();
    #pragma unroll
    for (int ss=0; ss<2; ++ss){
      int t2 = tid + ss*256;
      int i = t2>>5, ox = t2&31;
      float f0 = fx[2*i  ][ox];
      float f1 = fx[2*i+1][ox];
      float f2 = fx[2*i+2][ox];
      float f3 = fx[2*i+3][ox];
      float f4 = fx[2*i+4][ox];
      float fv0 = 0.25f*f0 + 0.75f*f1 + 0.75f*f2 + 0.25f*f3;
      float fv1 = 0.25f*f1 + 0.75f*f2 + 0.75f*f3 + 0.25f*f4;
      if (s >= 3){
        int oz = zg*8 + s - 3;
        __builtin_nontemporal_store(a0[ss][0] + 0.25f*fv0 + b, ob + (size_t)oz*1024 + (2*i  )*32 + ox);
        __builtin_nontemporal_store(a0[ss][1] + 0.25f*fv1 + b, ob + (size_t)oz*1024 + (2*i+1)*32 + ox);
      }
      a0[ss][0] = a1[ss][0] + 0.75f*fv0;  a1[ss][0] = a2[ss][0] + 0.75f*fv0;  a2[ss][0] = 0.25f*fv0;
      a0[ss][1] = a1[ss][1] + 0.75f*fv1;  a1[ss][1] = a2[ss][1] + 0.75f*fv1;  a2[ss][1] = 0.25f*fv1;
    }
    __syncthreads();
  }
}

extern "C" void kernel_launch(void* const* d_in, const int* in_sizes, int n_in,
                              void* d_out, int out_size, void* d_ws, size_t ws_size,
                              hipStream_t stream) {
  const float* x    = (const float*)d_in[0];
  const float* w    = (const float*)d_in[1];
  const float* bias = (const float*)d_in[2];
  float* out = (float*)d_out;

  float* zb = (float*)d_ws;
  u16* wh = (u16*)(zb + ZBF);
  u16* xh = wh + WRE;
  u16* yd = xh + XTE;
  size_t base = (size_t)ZBF*4 + (size_t)(WRE + XTE)*2;

  int nChunk = 1;
  if      (ws_size >= base + (size_t)8*128*VOLP*2) nChunk=8;
  else if (ws_size >= base + (size_t)4*128*VOLP*2) nChunk=4;
  else if (ws_size >= base + (size_t)2*128*VOLP*2) nChunk=2;

  prep_all<<<dim3(4480), 256, 0, stream>>>(x, w, xh, wh, zb);

  const u16* zb16 = (const u16*)zb;
  if (nChunk == 8){
    stage1f<<<dim3(2904,1,1),256,0,stream>>>(xh,wh,zb16,yd,0);
    stage2d<<<dim3(4,128,8),256,0,stream>>>(yd,bias,out,0);
  } else {
    for (int n0=0; n0<NBATCH; n0+=nChunk){
      stage1f<<<dim3(363,1,nChunk),256,0,stream>>>(xh,wh,zb16,yd,n0);
      stage2d<<<dim3(4,128,nChunk),256,0,stream>>>(yd,bias,out,n0);
    }
  }
}

// Round 25
// 182.737 us; speedup vs baseline: 1.0505x; 1.0505x over previous
//
#include <hip/hip_runtime.h>
#include <string.h>

typedef __attribute__((ext_vector_type(4))) float f32x4;
typedef __attribute__((ext_vector_type(8))) _Float16 f16x8;
typedef unsigned short u16;
typedef unsigned int   u32;

#define NBATCH 8
#define ICN 256
#define OCN 128
#define VOLP 36432     // padded per-(n,oc) y volume (elements)
#define WRE 884736     // 27*8*8*512 = 27*256*128
#define XTE 8388608    // 8*256*4096
#define ZBF 4096       // zero-buffer floats (16 KB)
// pool: staging 2 x 10880 B = 21760; epilogue transpose 4 waves x 32x33 f32 = 16896
#define S1POOL 21760

__host__ __device__ constexpr int cls_yoff2(int c){
  return (c==0)?0:(c==1)?5168:(c==2)?9792:(c==3)?14416:
         (c==4)?18768:(c==5)?23632:(c==6)?27984:32336;
}
__host__ __device__ constexpr int cls_nxyp(int c){
  return ((c&3)==0)?304:((c&3)==3)?256:272;
}

__device__ __forceinline__ u16 f2h(float v){
  _Float16 h = (_Float16)v;
  u16 u; memcpy(&u, &h, 2);
  return u;
}
__device__ __forceinline__ float h2f(u16 u){
  _Float16 h; memcpy(&h, &u, 2);
  return (float)h;
}

#define GLOAD16(gp, lp)                                                        \
  __builtin_amdgcn_global_load_lds(                                            \
      (const __attribute__((address_space(1))) void*)(gp),                     \
      (__attribute__((address_space(3))) void*)(lp), 16, 0, 0)

// ---- merged prep: blocks [0,1024) = prep_x ; [1024,4480) = prep_w ----
__global__ __launch_bounds__(256) void prep_all(const float* __restrict__ x,
                                                const float* __restrict__ w,
                                                u16* __restrict__ xh,
                                                u16* __restrict__ wh,
                                                float* __restrict__ zb){
  __shared__ u16 tile[256*33];
  const int tid = threadIdx.x;
  const int b = blockIdx.x;
  if (b < 1024){
    // prep_x: x[n][ic][4096] fp32 -> xh[n][icc8][4096 p][32 ic] f16 (coalesced)
    const int n = b >> 7, icc = (b >> 4) & 7, pc = b & 15;
    const float* xb = x + ((size_t)(n*256 + icc*32))*4096 + pc*256;
    #pragma unroll 4
    for (int r = 0; r < 32; ++r)
      tile[tid*33 + r] = f2h(xb[(size_t)r*4096 + tid]);
    __syncthreads();
    u16* ob = xh + ((size_t)(n*8 + icc))*131072 + pc*8192;
    #pragma unroll
    for (int j = 0; j < 4; ++j){
      int c = j*256 + tid;
      int p = c >> 2, il8 = (c & 3)*8;
      ushort4 lo, hi;
      lo.x = tile[p*33+il8+0]; lo.y = tile[p*33+il8+1];
      lo.z = tile[p*33+il8+2]; lo.w = tile[p*33+il8+3];
      hi.x = tile[p*33+il8+4]; hi.y = tile[p*33+il8+5];
      hi.z = tile[p*33+il8+6]; hi.w = tile[p*33+il8+7];
      *(ushort4*)&ob[c*8]     = lo;
      *(ushort4*)&ob[c*8 + 4] = hi;
    }
  } else {
    // prep_w: w[oc][ic][27] fp32 -> wh[tap27][icc8][og8][lane64][e8] f16
    const int bb = b - 1024;
    if (bb < 16) zb[bb*256 + tid] = 0.f;
    int idx = bb*256 + tid;   // WRE exactly
    int e = idx&7, ln=(idx>>3)&63, og=(idx>>9)&7, icc=(idx>>12)&7, tt=idx>>15;
    int oc = og*16 + (ln&15);
    int ic = icc*32 + ((ln>>4)&3)*8 + e;
    const int toffs[8] = {0,8,12,16,18,22,24,26};
    const int tcnt[8]  = {8,4,4,2,4,2,2,1};
    int c=0, t=0;
    #pragma unroll
    for (int cc=0; cc<8; ++cc)
      if (tt>=toffs[cc] && tt<toffs[cc]+tcnt[cc]){ c=cc; t=tt-toffs[cc]; }
    int ez=c>>2, ey=(c>>1)&1, ex=c&1;
    int ty=2-ey, tx=2-ex;
    int ax=t%tx, ay=(t/tx)%ty, az=t/(tx*ty);
    int qz = ez?1:(az?2:0), qy = ey?1:(ay?2:0), qx = ex?1:(ax?2:0);
    wh[idx] = f2h(w[((size_t)oc*ICN + ic)*27 + (qz*3+qy)*3+qx]);
  }
}

// ---- async A-plane staging: 680 chunks of 16 B; chunk s = icg*170 + pos ----
// wave wv stages icg-group wv (wave-uniform icg): [icg][pos] LDS layout
#define S1_ISSUE(BUFBYTE, ICCV, AZV)                                           \
  {                                                                            \
    _Pragma("unroll")                                                          \
    for (int j_=0; j_<3; ++j_){                                                \
      const int r_ = j_*64 + ln;                                               \
      if (r_ < 170){                                                           \
        const int s_ = wv*170 + r_;                                            \
        const int pos_ = r_;                                                   \
        const int xi_ = pos_%17, yi_ = pos_/17;                                \
        const int zc_ = EZ ? mz : (mz-1+(AZV));                                \
        const int yc_ = my0 + yi_ + (EY-1);                                    \
        const int xc_ = xi_ + (EX-1);                                          \
        const bool inb_ = (u32)zc_<16u && (u32)yc_<16u && (u32)xc_<16u;        \
        const size_t g_ = nbase + (size_t)(ICCV)*131072                        \
                        + (size_t)((zc_*256+yc_*16+xc_)*32 + wv*8);            \
        const u16* gh_ = inb_ ? (xh+g_) : zb16;                                \
        char* lh_ = pool + (BUFBYTE) + s_*16;                                  \
        GLOAD16(gh_, lh_);                                                     \
      }                                                                        \
    }                                                                          \
  }

// ---- stage 1 body: per-class dense conv via f16 MFMA; B-frags from L1/L2 ----
// block 256 (4 waves): wave = (mhalf = wv&1)*64m x (ochalf = wv>>1)*64oc
template<int EZ,int EY,int EX>
__device__ __forceinline__ void s1body(char* pool,
                                       const u16* __restrict__ xh,
                                       const u16* __restrict__ wh,
                                       const u16* __restrict__ zb16,
                                       u16* __restrict__ yd, int n0, int mt, int mz, int nl, int tid)
{
  constexpr int TZ=2-EZ, TY=2-EY, TX=2-EX;
  constexpr int DX=17-EX;
  constexpr int DY=17-EY;
  constexpr int NXY=DY*DX;
  constexpr int CLS = EZ*4+EY*2+EX;
  constexpr int YOFF = cls_yoff2(CLS);
  constexpr int NXYP = cls_nxyp(CLS);
  constexpr int W27 = (CLS==0)?0:(CLS==1)?8:(CLS==2)?12:(CLS==3)?16:
                      (CLS==4)?18:(CLS==5)?22:(CLS==6)?24:26;
  constexpr int NST = TZ*8;        // total plane-stages
  u16* AsU = (u16*)pool;           // per buffer: 5440 u16 = [icg4][pos170][e8]

  const int wv=tid>>6, ln=tid&63;
  const int mhalf = wv&1, ochalf = wv>>1;
  const int my0=(mt*128)/DX;

  int posA[4];
  #pragma unroll
  for (int fi=0; fi<4; ++fi){
    int m = mt*128 + mhalf*64 + fi*16 + (ln&15);
    if (m > NXY-1) m = NXY-1;      // clamp (stores guarded)
    int my=m/DX, mx=m-my*DX;
    posA[fi] = ((my-my0)*17 + mx)*8 + (ln>>4)*1360;   // [icg][pos] layout
  }

  f32x4 acc[4][4];
  #pragma unroll
  for (int i=0;i<4;++i)
    #pragma unroll
    for (int j=0;j<4;++j) acc[i][j]=(f32x4){0.f,0.f,0.f,0.f};

  const size_t nbase = (size_t)(n0+nl)*(ICN*4096);

  S1_ISSUE(0, 0, 0);

  int st = 0;
  #pragma unroll 1
  for (int icc=0; icc<8; ++icc){
    #pragma unroll
    for (int az=0; az<TZ; ++az){
      const int cur = st & 1;
      const bool have_next = (st+1) < NST;
      if (have_next){
        const int nicc = (az+1<TZ)?icc:(icc+1);
        const int naz  = (az+1<TZ)?(az+1):0;
        S1_ISSUE((cur^1)*10880, nicc, naz);
        asm volatile("s_waitcnt vmcnt(3)" ::: "memory");
      } else {
        asm volatile("s_waitcnt vmcnt(0)" ::: "memory");
      }
      asm volatile("s_barrier" ::: "memory");
      const int curo = cur*5440;

      #pragma unroll
      for (int ay=0; ay<TY; ++ay)
      #pragma unroll
      for (int ax=0; ax<TX; ++ax){
        const int t = (az*TY+ay)*TX+ax;
        const int toff = (ay*17+ax)*8;
        f16x8 ah[4];
        #pragma unroll
        for (int fi=0; fi<4; ++fi)
          ah[fi] = *(const f16x8*)&AsU[curo + posA[fi]+toff];
        const u16* bp = wh + (size_t)(((W27+t)*8+icc)*8)*512 + (ochalf*4)*512 + ln*8;
        f16x8 bh[4];
        #pragma unroll
        for (int og=0; og<4; ++og) bh[og] = *(const f16x8*)(bp + og*512);
        #pragma unroll
        for (int fi=0; fi<4; ++fi)
          #pragma unroll
          for (int og=0; og<4; ++og)
            acc[fi][og] = __builtin_amdgcn_mfma_f32_16x16x32_f16(ah[fi], bh[og], acc[fi][og],0,0,0);
      }
      asm volatile("s_barrier" ::: "memory");
      ++st;
    }
  }

  // epilogue: per-wave transpose via 32x33 buffer, 2 oc-halves x 2 m-passes
  float* tr = (float*)pool + wv*(32*33);
  #pragma unroll
  for (int h=0; h<2; ++h){
    #pragma unroll
    for (int pass=0; pass<2; ++pass){
      #pragma unroll
      for (int fi=0; fi<2; ++fi)
        #pragma unroll
        for (int og2=0; og2<2; ++og2){
          const int og = h*2 + og2;
          #pragma unroll
          for (int j=0; j<4; ++j)
            tr[(og2*16+(ln&15))*33 + fi*16 + (ln>>4)*4 + j] = acc[pass*2+fi][og][j];
        }
      int m = mt*128 + mhalf*64 + pass*32 + (ln&31);
      bool valid = m < NXY;
      size_t lbase = (size_t)YOFF + (size_t)mz*NXYP + (valid ? m : 0);
      #pragma unroll 4
      for (int i=0; i<16; ++i){
        int r = 2*i + (ln>>5);          // 0..31
        u16 v = f2h(tr[r*33 + (ln&31)]);
        int oc = ochalf*64 + h*32 + r;
        if (valid)
          __builtin_nontemporal_store(v, yd + (size_t)(nl*128 + oc)*VOLP + lbase);
      }
    }
  }
}

// ---- fused stage 1: class-major intra-XCD ordering (B-sharing L1 locality) ----
__global__ __launch_bounds__(256,3) void stage1f(const u16* __restrict__ xh,
                                                 const u16* __restrict__ wh,
                                                 const u16* __restrict__ zb16,
                                                 u16* __restrict__ yd, int n0){
  __shared__ __align__(16) char pool[S1POOL];
  int bid = blockIdx.x, nl, tid = threadIdx.x;
  if (gridDim.z == 1){ nl = bid & 7; bid >>= 3; }
  else               { nl = blockIdx.z; }
  // class-major: consecutive blocks on a CU share the SAME class -> same B
  if      (bid <  51){ int r=bid;     s1body<0,0,0>(pool,xh,wh,zb16,yd,n0,r%3,r/3,nl,tid); }
  else if (bid < 102){ int r=bid-51;  s1body<0,0,1>(pool,xh,wh,zb16,yd,n0,r%3,r/3,nl,tid); }
  else if (bid < 153){ int r=bid-102; s1body<0,1,0>(pool,xh,wh,zb16,yd,n0,r%3,r/3,nl,tid); }
  else if (bid < 187){ int r=bid-153; s1body<0,1,1>(pool,xh,wh,zb16,yd,n0,r%2,r/2,nl,tid); }
  else if (bid < 235){ int r=bid-187; s1body<1,0,0>(pool,xh,wh,zb16,yd,n0,r%3,r/3,nl,tid); }
  else if (bid < 283){ int r=bid-235; s1body<1,0,1>(pool,xh,wh,zb16,yd,n0,r%3,r/3,nl,tid); }
  else if (bid < 331){ int r=bid-283; s1body<1,1,0>(pool,xh,wh,zb16,yd,n0,r%3,r/3,nl,tid); }
  else               { int r=bid-331; s1body<1,1,1>(pool,xh,wh,zb16,yd,n0,r%2,r/2,nl,tid); }
}

// ---- stage 2: vectorized gather + paired separable FIR + bias ----
// grid (4 zg, 128 oc, n): 8 oz per block, 11 uz planes streamed
__global__ __launch_bounds__(256) void stage2d(const u16* __restrict__ yd, const float* __restrict__ bias,
                                               float* __restrict__ out, int n0){
  __shared__ float raw[33][36];
  __shared__ float fx[35][36];
  const int tid=threadIdx.x;
  const int zg=blockIdx.x, oc=blockIdx.y, nl=blockIdx.z;
  const u16* yb = yd + (size_t)(nl*128+oc)*VOLP;
  const float b = bias[oc];
  float* ob = out + (size_t)((n0+nl)*128+oc)*32768;
  for (int t2=tid; t2<1188; t2+=256) raw[t2/36][t2%36] = 0.f;
  for (int t2=tid; t2<1260; t2+=256) fx[t2/36][t2%36] = 0.f;
  __syncthreads();
  float a0[2][2]={{0,0},{0,0}}, a1[2][2]={{0,0},{0,0}}, a2[2][2]={{0,0},{0,0}};

  #pragma unroll 1
  for (int s=0; s<11; ++s){
    int uz = zg*8 - 1 + s;
    if ((u32)uz < 33u){
      const int cz = uz & 1, zi2 = uz >> 1;
      #pragma unroll 1
      for (int ch=tid; ch<273; ch+=256){
        #define GATH(CY,CX,CHL)                                                     \
        {                                                                           \
          constexpr int DXc = 17-(CX);                                              \
          constexpr int NXYc = (17-(CY))*DXc;                                       \
          constexpr int O0 = cls_yoff2((CY)*2+(CX));                                \
          constexpr int O1 = cls_yoff2(4+(CY)*2+(CX));                              \
          constexpr int PS = cls_nxyp((CY)*2+(CX));                                 \
          const int s2 = 4*(CHL);                                                   \
          const int r0 = s2/DXc;                                                    \
          const int c0 = s2 - r0*DXc;                                               \
          const u16* sp = yb + (cz?O1:O0) + zi2*PS + s2;                            \
          ushort4 v = *(const ushort4*)sp;                                          \
          u16 ve[4] = {v.x, v.y, v.z, v.w};                                         \
          _Pragma("unroll")                                                         \
          for (int e=0; e<4; ++e){                                                  \
            int c = c0+e, rr = r0;                                                  \
            if (c >= DXc){ c -= DXc; rr += 1; }                                     \
            if (s2+e < NXYc) raw[2*rr+(CY)][2*c+(CX)+1] = h2f(ve[e]);               \
          }                                                                         \
        }
        if      (ch <  73) GATH(0,0,ch)
        else if (ch < 141) GATH(0,1,ch-73)
        else if (ch < 209) GATH(1,0,ch-141)
        else               GATH(1,1,ch-209)
        #undef GATH
      }
    } else {
      for (int t2=tid; t2<1188; t2+=256) raw[t2/36][t2%36] = 0.f;
    }
    __syncthreads();
    #pragma unroll 1
    for (int t2=tid; t2<528; t2+=256){
      int uy = t2>>4, j = t2&15;
      float2 A = *(const float2*)&raw[uy][2*j];
      float2 B = *(const float2*)&raw[uy][2*j+2];
      float  Cv = raw[uy][2*j+4];
      float f0 = 0.25f*A.x + 0.75f*A.y + 0.75f*B.x + 0.25f*B.y;
      float f1 = 0.25f*A.y + 0.75f*B.x + 0.75f*B.y + 0.25f*Cv;
      *(float2*)&fx[uy+1][2*j] = make_float2(f0, f1);
    }
    __syncthreads();
    #pragma unroll
    for (int ss=0; ss<2; ++ss){
      int t2 = tid + ss*256;
      int i = t2>>5, ox = t2&31;
      float f0 = fx[2*i  ][ox];
      float f1 = fx[2*i+1][ox];
      float f2 = fx[2*i+2][ox];
      float f3 = fx[2*i+3][ox];
      float f4 = fx[2*i+4][ox];
      float fv0 = 0.25f*f0 + 0.75f*f1 + 0.75f*f2 + 0.25f*f3;
      float fv1 = 0.25f*f1 + 0.75f*f2 + 0.75f*f3 + 0.25f*f4;
      if (s >= 3){
        int oz = zg*8 + s - 3;
        __builtin_nontemporal_store(a0[ss][0] + 0.25f*fv0 + b, ob + (size_t)oz*1024 + (2*i  )*32 + ox);
        __builtin_nontemporal_store(a0[ss][1] + 0.25f*fv1 + b, ob + (size_t)oz*1024 + (2*i+1)*32 + ox);
      }
      a0[ss][0] = a1[ss][0] + 0.75f*fv0;  a1[ss][0] = a2[ss][0] + 0.75f*fv0;  a2[ss][0] = 0.25f*fv0;
      a0[ss][1] = a1[ss][1] + 0.75f*fv1;  a1[ss][1] = a2[ss][1] + 0.75f*fv1;  a2[ss][1] = 0.25f*fv1;
    }
    __syncthreads();
  }
}

extern "C" void kernel_launch(void* const* d_in, const int* in_sizes, int n_in,
                              void* d_out, int out_size, void* d_ws, size_t ws_size,
                              hipStream_t stream) {
  const float* x    = (const float*)d_in[0];
  const float* w    = (const float*)d_in[1];
  const float* bias = (const float*)d_in[2];
  float* out = (float*)d_out;

  float* zb = (float*)d_ws;
  u16* wh = (u16*)(zb + ZBF);
  u16* xh = wh + WRE;
  u16* yd = xh + XTE;
  size_t base = (size_t)ZBF*4 + (size_t)(WRE + XTE)*2;

  int nChunk = 1;
  if      (ws_size >= base + (size_t)8*128*VOLP*2) nChunk=8;
  else if (ws_size >= base + (size_t)4*128*VOLP*2) nChunk=4;
  else if (ws_size >= base + (size_t)2*128*VOLP*2) nChunk=2;

  prep_all<<<dim3(4480), 256, 0, stream>>>(x, w, xh, wh, zb);

  const u16* zb16 = (const u16*)zb;
  if (nChunk == 8){
    stage1f<<<dim3(2904,1,1),256,0,stream>>>(xh,wh,zb16,yd,0);
    stage2d<<<dim3(4,128,8),256,0,stream>>>(yd,bias,out,0);
  } else {
    for (int n0=0; n0<NBATCH; n0+=nChunk){
      stage1f<<<dim3(363,1,nChunk),256,0,stream>>>(xh,wh,zb16,yd,n0);
      stage2d<<<dim3(4,128,nChunk),256,0,stream>>>(yd,bias,out,n0);
    }
  }
}